// Round 7
// baseline (466.389 us; speedup 1.0000x reference)
//
#include <hip/hip_runtime.h>
#include <hip/hip_fp16.h>

#define NBINS 32
#define DIM 64
#define RANGE_MIN_F (-5.0f)
#define RANGE_MAX_F (5.0f)
#define NCELL 64
#define LUT_STRIDE 68            // (17d + g/4) % 32 spreads LUT rows across banks
#define BLOCK 512
#define GRID 768                 // persistent: 3 blocks/CU on 256 CUs
#define INV_CW 6.4f              // NCELL / (RANGE_MAX - RANGE_MIN)
#define GBIAS 32.0f              // -RANGE_MIN * INV_CW

typedef float f32x4 __attribute__((ext_vector_type(4)));   // native vector: OK for
                                                           // __builtin_nontemporal_*

// LDS budget per block (static):
//   s_ap  DIM*NBINS*8  = 16384 B   {xk[p], xk[p+1]}       - selection pair (b64)
//   s_b   DIM*NBINS*16 = 32768 B   {1/w, yk, h, f16x2(dk,dk1)} - full record (b128)
//   s_lut DIM*68       =  4352 B
//   total 53504 B -> 3 blocks/CU (156.7 KB of 160 KB), 24 waves/CU
//
// R5 post-mortem: depth-2 prefetch was NULL (438.7 -> 439.3) => not load-latency
// bound.  Revised model: old layout moved 48 B / 5 LDS instrs per element
// (~0.65 cy/elem/CU = ~71 us LDS-pipe), co-bottleneck with ~85 us HBM.  This
// layout moves 24 B / 3 instrs (~0.37 cy = ~39 us) by exploiting
// t1>=1  <=>  xv >= xk[p+1]  (no divide needed for the advance test), so one
// b64 selects the bin and one b128 fetches the selected record.  Slopes are
// f16-packed (dk ~ ln2, rel err 5e-4 -> y err ~4e-5 << 0.03125 tol).

__global__ __launch_bounds__(BLOCK, 6) void rqs_fused(
        const float* __restrict__ x,
        const float* __restrict__ bw,
        const float* __restrict__ bh,
        const float* __restrict__ ks,
        float* __restrict__ out,
        int total) {
    __shared__ float2 s_ap[DIM * NBINS];
    __shared__ float4 s_b [DIM * NBINS];
    __shared__ unsigned char s_lut[DIM * LUT_STRIDE];

    const int t = threadIdx.x;

    // ---- phase 1: build tables (2 groups of 64 threads) ----
    if (t < DIM) {
        // widths: knot pairs + 1/w component of the record
        const int d = t, sw = d >> 2;
        float acc = 0.0f;
        #pragma unroll
        for (int k = 0; k < NBINS; ++k) {
            float w = bw[d * NBINS + k];
            int s = d * NBINS + ((k + sw) & (NBINS - 1));
            s_ap[s] = make_float2(RANGE_MIN_F + acc, RANGE_MIN_F + acc + w);
            s_b[s].x = __builtin_amdgcn_rcpf(w);      // .x only: disjoint from group B
            acc += w;
        }
    } else if (t < 2 * DIM) {
        // heights + slopes: {yk, h, pack(dk,dk1)} components
        const int d = t - DIM, sw = d >> 2;
        float acc = 0.0f, prev = 1.0f;                // kd[0] = 1
        #pragma unroll
        for (int k = 0; k < NBINS; ++k) {
            float h = bh[d * NBINS + k];
            float nxt = (k < NBINS - 1) ? ks[d * (NBINS - 1) + k] : 1.0f;
            int s = d * NBINS + ((k + sw) & (NBINS - 1));
            s_b[s].y = RANGE_MIN_F + acc;
            s_b[s].z = h;
            __half2 hp = __floats2half2_rn(prev, nxt);
            s_b[s].w = __builtin_bit_cast(float, hp);
            acc += h; prev = nxt;
        }
    }
    __syncthreads();

    // ---- phase 2: LUT: lut[d][g] = max{p in [0,31] : kx[p] <= cellLeft(g)} ----
    const float cellw = (RANGE_MAX_F - RANGE_MIN_F) / (float)NCELL;
    #pragma unroll
    for (int e = 0; e < (DIM * NCELL + BLOCK - 1) / BLOCK; ++e) {
        int j = t + e * BLOCK;
        if (j < DIM * NCELL) {
            int d = j >> 6, g = j & (NCELL - 1);
            int sw = d >> 2;
            float cl = RANGE_MIN_F + (float)g * cellw;
            int p = 0;
            #pragma unroll
            for (int s = 16; s >= 1; s >>= 1) {
                float kxs = s_ap[d * NBINS + ((p + s + sw) & (NBINS - 1))].x;
                p += (kxs <= cl) ? s : 0;
            }
            s_lut[d * LUT_STRIDE + g] = (unsigned char)p;
        }
    }
    __syncthreads();

    // ---- per-element evaluator: LUT byte -> b64 pair -> b128 record ----
    auto eval1 = [&](float xv, int d) -> float {
        const int sw = d >> 2;
        float gf = fmaf(xv, INV_CW, GBIAS);
        gf = fminf(fmaxf(gf, 0.0f), (float)(NCELL - 1));   // v_med3
        int g = (int)gf;
        int p = (int)s_lut[d * LUT_STRIDE + g];
        float2 ap = s_ap[d * NBINS + ((p + sw) & (NBINS - 1))];
        bool adv = (xv >= ap.y) && (p < NBINS - 1);   // t1>=1 <=> xv >= xk[p+1]
        int sel = p + (adv ? 1 : 0);
        float xks = adv ? ap.y : ap.x;
        float4 b = s_b[d * NBINS + ((sel + sw) & (NBINS - 1))];
        float tt0 = (xv - xks) * b.x;                 // t in the selected bin
        // safety fixup for pathological >2-knot cells (~never taken)
        while (__builtin_expect((tt0 >= 1.0f) && (sel < NBINS - 1), 0)) {
            ++sel;
            int ix = d * NBINS + ((sel + sw) & (NBINS - 1));
            xks = s_ap[ix].x;
            b = s_b[ix];
            tt0 = (xv - xks) * b.x;
        }
        __half2 hp = __builtin_bit_cast(__half2, b.w);
        float dk  = __low2float(hp);
        float dk1 = __high2float(hp);
        float iw = b.x, yk = b.y, h = b.z;
        float sm  = h * iw;                           // bin mean slope s = h/w
        float tt  = tt0 * (1.0f - tt0);
        float num = h * fmaf(dk, tt, sm * tt0 * tt0);
        float den = fmaf(fmaf(-2.0f, sm, dk + dk1), tt, sm);
        float y   = fmaf(num, __builtin_amdgcn_rcpf(den), yk);
        bool inside = (xv >= RANGE_MIN_F) && (tt0 <= 1.0f);
        return inside ? y : xv;
    };

    auto eval4 = [&](f32x4 c, int d0) -> f32x4 {
        f32x4 r;
        r[0] = eval1(c[0], d0 + 0);
        r[1] = eval1(c[1], d0 + 1);
        r[2] = eval1(c[2], d0 + 2);
        r[3] = eval1(c[3], d0 + 3);
        return r;
    };

    // ---- phase 3: dual-stream float4, persistent grid-stride, depth-2 prefetch ----
    // Streams v and v+TOTV; 4*TOTV % 64 == 0 so both share d0 (same LDS rows).
    const int tid  = blockIdx.x * BLOCK + t;
    const int TOTV = GRID * BLOCK;
    const int d0   = (4 * tid) & (DIM - 1);
    const int nvec = total >> 2;
    const f32x4* X4 = (const f32x4*)x;
    f32x4* O4 = (f32x4*)out;

    int v = tid;
    if (v < nvec) {
        f32x4 c0 = __builtin_nontemporal_load(&X4[v]);
        bool has1 = (v + TOTV < nvec);
        f32x4 c1 = c0;
        if (has1) c1 = __builtin_nontemporal_load(&X4[v + TOTV]);
        while (true) {
            int v2 = v + 2 * TOTV;
            bool m0 = (v2 < nvec);
            bool m1 = (v2 + TOTV < nvec);
            f32x4 p0 = c0, p1 = c1;
            if (m0) p0 = __builtin_nontemporal_load(&X4[v2]);          // 2 loads in
            if (m1) p1 = __builtin_nontemporal_load(&X4[v2 + TOTV]);   // flight here
            f32x4 r0 = eval4(c0, d0);
            __builtin_nontemporal_store(r0, &O4[v]);
            if (has1) {
                f32x4 r1 = eval4(c1, d0);
                __builtin_nontemporal_store(r1, &O4[v + TOTV]);
            }
            if (!m0) break;
            c0 = p0; c1 = p1; has1 = m1; v = v2;
        }
    }
    // tail (total % 4 != 0 safety; zero iterations for this problem size)
    int rem = total & 3;
    if (rem && tid < rem) {
        int i = (total & ~3) + tid;
        out[i] = eval1(x[i], i & (DIM - 1));
    }
}

extern "C" void kernel_launch(void* const* d_in, const int* in_sizes, int n_in,
                              void* d_out, int out_size, void* d_ws, size_t ws_size,
                              hipStream_t stream) {
    const float* x  = (const float*)d_in[0];
    const float* bw = (const float*)d_in[1];
    const float* bh = (const float*)d_in[2];
    const float* ks = (const float*)d_in[3];
    float* out = (float*)d_out;

    rqs_fused<<<GRID, BLOCK, 0, stream>>>(x, bw, bh, ks, out, out_size);
}

// Round 11
// 433.981 us; speedup vs baseline: 1.0747x; 1.0747x over previous
//
#include <hip/hip_runtime.h>
#include <hip/hip_fp16.h>

#define NBINS 32
#define DIM 64
#define RANGE_MIN_F (-5.0f)
#define RANGE_MAX_F (5.0f)
#define NCELL 64
#define LUT_STRIDE 68            // (17d + g/4) % 32 spreads LUT rows across banks
#define BLOCK 512
#define GRID 768                 // persistent: 3 blocks/CU on 256 CUs
#define INV_CW 6.4f              // NCELL / (RANGE_MAX - RANGE_MIN)
#define GBIAS 32.0f              // -RANGE_MIN * INV_CW

typedef float f32x4 __attribute__((ext_vector_type(4)));   // native vector: OK for
                                                           // __builtin_nontemporal_*

// LDS budget per block (static):
//   s_rec DIM*NBINS*16 = 32768 B  {xk f32, yk f32, f16x2(iw,dk), f16x2(h,dk1)}
//   s_lut DIM*68       =  4352 B
//   total 37120 B -> LDS allows 4 blocks/CU; VGPR (85) caps at 24 waves/CU.
//
// R7 post-mortem: 3-level serial LDS chain (LUT -> b64 -> b128) regressed the
// kernel ~111 -> ~131 us despite lower traffic: latency topology beat
// throughput.  This version restores the 2-level topology (LUT -> two
// PARALLEL b128 at p, p+1) while still cutting traffic to 32 B / 2 instrs
// per element by f16-packing {1/w, h, dk, dk1} into one 16 B record.
// f16 error audit: iw -> y err ~5e-4, h -> ~1.5e-4, dk/dk1 -> ~4e-5; all
// << tol (R7 confirmed absmax 0.03125 is unchanged by f16 fields).

__global__ __launch_bounds__(BLOCK, 6) void rqs_fused(
        const float* __restrict__ x,
        const float* __restrict__ bw,
        const float* __restrict__ bh,
        const float* __restrict__ ks,
        float* __restrict__ out,
        int total) {
    __shared__ float4 s_rec[DIM * NBINS];
    __shared__ unsigned char s_lut[DIM * LUT_STRIDE];

    const int t = threadIdx.x;

    // ---- phase 1: build records (2 groups of 64 threads, disjoint components) ----
    if (t < DIM) {
        // widths + left slopes: .x = xk, .z = pack(1/w, dk)
        const int d = t, sw = d >> 2;
        float acc = 0.0f;
        #pragma unroll
        for (int k = 0; k < NBINS; ++k) {
            float w  = bw[d * NBINS + k];
            float dk = (k == 0) ? 1.0f : ks[d * (NBINS - 1) + (k - 1)];
            int s = d * NBINS + ((k + sw) & (NBINS - 1));
            s_rec[s].x = RANGE_MIN_F + acc;
            __half2 hz = __floats2half2_rn(__builtin_amdgcn_rcpf(w), dk);
            s_rec[s].z = __builtin_bit_cast(float, hz);
            acc += w;
        }
    } else if (t < 2 * DIM) {
        // heights + right slopes: .y = yk, .w = pack(h, dk1)
        const int d = t - DIM, sw = d >> 2;
        float acc = 0.0f;
        #pragma unroll
        for (int k = 0; k < NBINS; ++k) {
            float h   = bh[d * NBINS + k];
            float dk1 = (k == NBINS - 1) ? 1.0f : ks[d * (NBINS - 1) + k];
            int s = d * NBINS + ((k + sw) & (NBINS - 1));
            s_rec[s].y = RANGE_MIN_F + acc;
            __half2 hw = __floats2half2_rn(h, dk1);
            s_rec[s].w = __builtin_bit_cast(float, hw);
            acc += h;
        }
    }
    __syncthreads();

    // ---- phase 2: LUT: lut[d][g] = max{p in [0,31] : kx[p] <= cellLeft(g)} ----
    const float cellw = (RANGE_MAX_F - RANGE_MIN_F) / (float)NCELL;
    #pragma unroll
    for (int e = 0; e < (DIM * NCELL + BLOCK - 1) / BLOCK; ++e) {
        int j = t + e * BLOCK;
        if (j < DIM * NCELL) {
            int d = j >> 6, g = j & (NCELL - 1);
            int sw = d >> 2;
            float cl = RANGE_MIN_F + (float)g * cellw;
            int p = 0;
            #pragma unroll
            for (int s = 16; s >= 1; s >>= 1) {
                float kxs = s_rec[d * NBINS + ((p + s + sw) & (NBINS - 1))].x;
                p += (kxs <= cl) ? s : 0;
            }
            s_lut[d * LUT_STRIDE + g] = (unsigned char)p;
        }
    }
    __syncthreads();

    // ---- per-element evaluator: LUT byte -> 2 PARALLEL b128 -> packed select ----
    auto eval1 = [&](float xv, int d) -> float {
        const int sw = d >> 2;
        float gf = fmaf(xv, INV_CW, GBIAS);
        gf = fminf(fmaxf(gf, 0.0f), (float)(NCELL - 1));   // v_med3
        int g = (int)gf;
        int p = (int)s_lut[d * LUT_STRIDE + g];
        int ix1 = d * NBINS + ((p + sw) & (NBINS - 1));
        int ix2 = d * NBINS + ((p + 1 + sw) & (NBINS - 1)); // wraps at p==31; dead then
        float4 r1 = s_rec[ix1];                             // independent: both issue
        float4 r2 = s_rec[ix2];                             // before one lgkmcnt wait
        bool adv = (xv >= r2.x) && (p < NBINS - 1);         // t1>=1 <=> xv >= xk[p+1]
        int sel = p + (adv ? 1 : 0);
        float xk = adv ? r2.x : r1.x;
        float yk = adv ? r2.y : r1.y;
        float pz = adv ? r2.z : r1.z;                       // select packed words,
        float pw = adv ? r2.w : r1.w;                       // convert once
        __half2 hz = __builtin_bit_cast(__half2, pz);
        __half2 hw = __builtin_bit_cast(__half2, pw);
        float iw  = __low2float(hz),  dk  = __high2float(hz);
        float h   = __low2float(hw),  dk1 = __high2float(hw);
        float tt0 = (xv - xk) * iw;
        // safety fixup for pathological >2-knot cells (~never taken)
        while (__builtin_expect((tt0 >= 1.0f) && (sel < NBINS - 1), 0)) {
            ++sel;
            float4 rr = s_rec[d * NBINS + ((sel + sw) & (NBINS - 1))];
            xk = rr.x; yk = rr.y;
            __half2 a = __builtin_bit_cast(__half2, rr.z);
            __half2 b = __builtin_bit_cast(__half2, rr.w);
            iw = __low2float(a); dk = __high2float(a);
            h  = __low2float(b); dk1 = __high2float(b);
            tt0 = (xv - xk) * iw;
        }
        float sm  = h * iw;                                 // bin mean slope s = h/w
        float tt  = tt0 * (1.0f - tt0);
        float num = h * fmaf(dk, tt, sm * tt0 * tt0);
        float den = fmaf(fmaf(-2.0f, sm, dk + dk1), tt, sm);
        float y   = fmaf(num, __builtin_amdgcn_rcpf(den), yk);
        bool inside = (xv >= RANGE_MIN_F) && (tt0 <= 1.0f);
        return inside ? y : xv;
    };

    // ---- phase 3: float4 streaming, persistent grid-stride, prefetch 1 deep ----
    const int tid  = blockIdx.x * BLOCK + t;
    const int TOTV = GRID * BLOCK;                 // float4 stride; 4*TOTV % 64 == 0
    const int d0   = (4 * tid) & (DIM - 1);        // dim of lane's first sub-element
    const int nvec = total >> 2;
    const f32x4* X4 = (const f32x4*)x;
    f32x4* O4 = (f32x4*)out;

    int v = tid;
    if (v < nvec) {
        f32x4 cur = __builtin_nontemporal_load(&X4[v]);
        while (true) {
            int vn = v + TOTV;
            bool more = (vn < nvec);
            f32x4 nxt = cur;
            if (more) nxt = __builtin_nontemporal_load(&X4[vn]);  // in flight during compute
            f32x4 r;
            r[0] = eval1(cur[0], d0 + 0);
            r[1] = eval1(cur[1], d0 + 1);
            r[2] = eval1(cur[2], d0 + 2);
            r[3] = eval1(cur[3], d0 + 3);
            __builtin_nontemporal_store(r, &O4[v]);
            if (!more) break;
            cur = nxt; v = vn;
        }
    }
    // tail (total % 4 != 0 safety; zero iterations for this problem size)
    int rem = total & 3;
    if (rem && tid < rem) {
        int i = (total & ~3) + tid;
        out[i] = eval1(x[i], i & (DIM - 1));
    }
}

extern "C" void kernel_launch(void* const* d_in, const int* in_sizes, int n_in,
                              void* d_out, int out_size, void* d_ws, size_t ws_size,
                              hipStream_t stream) {
    const float* x  = (const float*)d_in[0];
    const float* bw = (const float*)d_in[1];
    const float* bh = (const float*)d_in[2];
    const float* ks = (const float*)d_in[3];
    float* out = (float*)d_out;

    rqs_fused<<<GRID, BLOCK, 0, stream>>>(x, bw, bh, ks, out, out_size);
}